// Round 5
// baseline (1258.218 us; speedup 1.0000x reference)
//
#include <hip/hip_runtime.h>
#include <math.h>

#define H 768
#define NH 12
#define DH 64
#define SEQ 2048
#define BATCH 2
#define TOK (BATCH*SEQ)   // 4096 rows
#define LAYERS 6
#define VOCAB 50257

// preconverted bf16 weight layout (per layer, element offsets)
#define WOFF_QKV   0
#define WSZ_QKV    (2304*768)
#define WOFF_DENSE (WOFF_QKV + WSZ_QKV)
#define WSZ_DENSE  (768*768)
#define WOFF_FC1   (WOFF_DENSE + WSZ_DENSE)
#define WSZ_FC1    (1536*768)
#define WOFF_FC2   (WOFF_FC1 + WSZ_FC1)
#define WSZ_FC2    (768*1536)
#define WSTRIDE    (WOFF_FC2 + WSZ_FC2)   // 4718592 elems/layer

typedef __attribute__((ext_vector_type(8))) short short8;
typedef __attribute__((ext_vector_type(4))) float floatx4;

__device__ __forceinline__ float bf2f(unsigned short u) {
    union { unsigned int i; float f; } v; v.i = ((unsigned int)u) << 16; return v.f;
}
__device__ __forceinline__ unsigned short f2b(float f) {
    union { float f; unsigned int i; } v; v.f = f;
    unsigned int u = v.i;
    return (unsigned short)((u + 0x7FFFu + ((u >> 16) & 1u)) >> 16);  // RNE
}
__device__ __forceinline__ void gload_lds16(const void* g, void* lds) {
    __builtin_amdgcn_global_load_lds((const __attribute__((address_space(1))) unsigned int*)g,
                                     (__attribute__((address_space(3))) unsigned int*)lds,
                                     16, 0, 0);
}

// counted-vmcnt + raw barrier in ONE asm block (memory clobber keeps all
// memory ops on their side; vmcnt before s_barrier so all waves' loads are
// visible at barrier exit). N = loads allowed to stay in flight.
template <int N>
__device__ __forceinline__ void waitbar() {
    asm volatile("s_waitcnt vmcnt(%0)\ns_barrier" :: "n"(N) : "memory");
}

// ---------------------------------------------------------------- embed
__global__ __launch_bounds__(256) void embed_kernel(const int* __restrict__ ids,
                                                    const float* __restrict__ wte,
                                                    const float* __restrict__ wpe,
                                                    float* __restrict__ x) {
    int row = blockIdx.x;
    int s = row & (SEQ - 1);
    int id = ids[row];
    const float* wrow = wte + (size_t)id * H;
    const float* prow = wpe + (size_t)s * H;
    float* xrow = x + (size_t)row * H;
    for (int i = threadIdx.x; i < H; i += 256)
        xrow[i] = wrow[i] + prow[i];
}

// ---------------------------------------------------------------- layernorm
template <bool BF>
__global__ __launch_bounds__(256) void ln_kernel(const float* __restrict__ x,
                                                 const float* __restrict__ g,
                                                 const float* __restrict__ bb,
                                                 void* __restrict__ outv,
                                                 int rs, int ro) {
    __shared__ float red[4];
    __shared__ float mean_s, rstd_s;
    int row = blockIdx.x * rs + ro;
    const float* xr = x + (size_t)row * H;
    int t = threadIdx.x;
    float v0 = xr[t], v1 = xr[t + 256], v2 = xr[t + 512];
    float s = v0 + v1 + v2;
    #pragma unroll
    for (int off = 32; off > 0; off >>= 1) s += __shfl_down(s, off);
    int lane = t & 63, wid = t >> 6;
    if (lane == 0) red[wid] = s;
    __syncthreads();
    if (t == 0) mean_s = (red[0] + red[1] + red[2] + red[3]) * (1.0f / 768.0f);
    __syncthreads();
    float m = mean_s;
    float d0 = v0 - m, d1 = v1 - m, d2 = v2 - m;
    float q = d0 * d0 + d1 * d1 + d2 * d2;
    #pragma unroll
    for (int off = 32; off > 0; off >>= 1) q += __shfl_down(q, off);
    if (lane == 0) red[wid] = q;
    __syncthreads();
    if (t == 0) rstd_s = rsqrtf((red[0] + red[1] + red[2] + red[3]) * (1.0f / 768.0f) + 1e-12f);
    __syncthreads();
    float r = rstd_s;
    float o0 = d0 * r * g[t]       + bb[t];
    float o1 = d1 * r * g[t + 256] + bb[t + 256];
    float o2 = d2 * r * g[t + 512] + bb[t + 512];
    if (BF) {
        unsigned short* orow = (unsigned short*)outv + (size_t)blockIdx.x * H;
        orow[t] = f2b(o0); orow[t + 256] = f2b(o1); orow[t + 512] = f2b(o2);
    } else {
        float* orow = (float*)outv + (size_t)blockIdx.x * H;
        orow[t] = o0; orow[t + 256] = o1; orow[t + 512] = o2;
    }
}

// ---------------------------------------------------------------- all-layer weight convert: fp32[K,N] -> bf16[N,K]
__global__ __launch_bounds__(256) void wconv_all(const float* __restrict__ qkv_w,
                                                 const float* __restrict__ dense_w,
                                                 const float* __restrict__ fc1_w,
                                                 const float* __restrict__ fc2_w,
                                                 unsigned short* __restrict__ wt) {
    __shared__ float tile[64][65];
    int bid = blockIdx.x;
    int l = bid / 1152;
    int r = bid % 1152;
    const float* W; unsigned short* D; int K, N, tn, tk;
    if (r < 432)      { W = qkv_w  + (size_t)l * 768 * 2304; D = wt + (size_t)l * WSTRIDE + WOFF_QKV;
                        K = 768;  N = 2304; tn = r % 36; tk = r / 36; }
    else if (r < 576) { r -= 432; W = dense_w + (size_t)l * 768 * 768; D = wt + (size_t)l * WSTRIDE + WOFF_DENSE;
                        K = 768;  N = 768;  tn = r % 12; tk = r / 12; }
    else if (r < 864) { r -= 576; W = fc1_w + (size_t)l * 768 * 1536; D = wt + (size_t)l * WSTRIDE + WOFF_FC1;
                        K = 768;  N = 1536; tn = r % 24; tk = r / 24; }
    else              { r -= 864; W = fc2_w + (size_t)l * 1536 * 768; D = wt + (size_t)l * WSTRIDE + WOFF_FC2;
                        K = 1536; N = 768;  tn = r % 12; tk = r / 12; }
    int n0 = tn * 64, k0 = tk * 64;
    int t = threadIdx.x;
    int rr = t >> 4, c = (t & 15) << 2;
    #pragma unroll
    for (int i = 0; i < 4; ++i) {
        float4 v = *(const float4*)(W + (size_t)(k0 + rr + 16 * i) * N + n0 + c);
        tile[rr + 16 * i][c + 0] = v.x; tile[rr + 16 * i][c + 1] = v.y;
        tile[rr + 16 * i][c + 2] = v.z; tile[rr + 16 * i][c + 3] = v.w;
    }
    __syncthreads();
    #pragma unroll
    for (int i = 0; i < 4; ++i) {
        int n = rr + 16 * i;
        ushort4 o;
        o.x = f2b(tile[c + 0][n]); o.y = f2b(tile[c + 1][n]);
        o.z = f2b(tile[c + 2][n]); o.w = f2b(tile[c + 3][n]);
        *(ushort4*)(D + (size_t)(n0 + n) * K + k0 + c) = o;
    }
}

// ---------------------------------------------------------------- bf16 MFMA GEMM
// GBK=64, XOR-swizzled LDS, 3-buffer counted-vmcnt pipeline (T4): one full
// tile's loads stay in flight across every barrier; no vmcnt(0) drain in the
// main loop. C[M,N] = A[M,K] @ Bt[N,K]^T
// MODE 0: qkv epilogue (+bias; Q cols pre-scaled 1/8; V cols -> vtb transposed) -> bf16
// MODE 1: +bias+res -> fp32 ; MODE 2: gelu -> bf16
#define GBK 64
template <int TM, int TN, int MODE>
__global__ __launch_bounds__(256) void gemm_bf16(const unsigned short* __restrict__ A,
                                                 const unsigned short* __restrict__ Bt,
                                                 const float* __restrict__ bias,
                                                 const float* __restrict__ res,
                                                 void* __restrict__ Cv,
                                                 unsigned short* __restrict__ vtb,
                                                 int M, int N, int K) {
    constexpr int MI = TM / 32, NI = TN / 32;
    constexpr int ALD = TM / 32, BLD = TN / 32;   // 8-row gloads per wave
    constexpr int LPS = ALD + BLD;                // loads per stage (4 or 6)
    __shared__ short As[3][TM * GBK];
    __shared__ short Bs[3][TN * GBK];
    int t = threadIdx.x;
    int w = t >> 6, lane = t & 63;
    int wr = w >> 1, wc = w & 1;
    int l16 = lane & 15, quad = lane >> 4;
    int l7 = l16 & 7;
    int lrow = lane >> 3;                         // 0..7
    int swsrc = ((lane & 7) ^ lrow) * 8;          // pre-swizzled source col
    int bm = blockIdx.y * TM, bn = blockIdx.x * TN;

    floatx4 acc[MI][NI] = {};
    const unsigned short* Aw[ALD];
    const unsigned short* Bw[BLD];
    #pragma unroll
    for (int j = 0; j < ALD; ++j)
        Aw[j] = A + (size_t)(bm + w * (TM / 4) + j * 8 + lrow) * K + swsrc;
    #pragma unroll
    for (int j = 0; j < BLD; ++j)
        Bw[j] = Bt + (size_t)(bn + w * (TN / 4) + j * 8 + lrow) * K + swsrc;

    auto stage = [&](int b, int k0) {
        #pragma unroll
        for (int j = 0; j < ALD; ++j)
            gload_lds16(Aw[j] + k0, (char*)&As[b][0] + (w * (TM / 4) + j * 8) * (GBK * 2));
        #pragma unroll
        for (int j = 0; j < BLD; ++j)
            gload_lds16(Bw[j] + k0, (char*)&Bs[b][0] + (w * (TN / 4) + j * 8) * (GBK * 2));
    };
    auto compute = [&](int b) {
        short8 af[2][MI], bfr[2][NI];
        #pragma unroll
        for (int kk = 0; kk < 2; ++kk) {
            #pragma unroll
            for (int mi = 0; mi < MI; ++mi)
                af[kk][mi] = *(const short8*)&As[b][(wr * (TM / 2) + mi * 16 + l16) * GBK + ((kk * 4 + quad) ^ l7) * 8];
            #pragma unroll
            for (int ni = 0; ni < NI; ++ni)
                bfr[kk][ni] = *(const short8*)&Bs[b][(wc * (TN / 2) + ni * 16 + l16) * GBK + ((kk * 4 + quad) ^ l7) * 8];
        }
        #pragma unroll
        for (int kk = 0; kk < 2; ++kk)
            #pragma unroll
            for (int mi = 0; mi < MI; ++mi)
                #pragma unroll
                for (int ni = 0; ni < NI; ++ni)
                    acc[mi][ni] = __builtin_amdgcn_mfma_f32_16x16x32_bf16(af[kk][mi], bfr[kk][ni], acc[mi][ni], 0, 0, 0);
    };

    const int KT = K / GBK;   // 12 or 24 (always >= 3)
    // prologue: 2 tiles in flight; wait tile0 only (tile1's LPS stay out)
    stage(0, 0);
    stage(1, GBK);
    waitbar<LPS>();
    int cur = 0;
    for (int kt = 0; kt < KT - 2; ++kt) {
        int sb = cur + 2; if (sb >= 3) sb -= 3;
        stage(sb, (kt + 2) * GBK);     // overwrites buf last read at kt-1 (barrier-separated)
        compute(cur);
        waitbar<LPS>();                // tile kt+1 landed; tile kt+2 still in flight
        cur += 1; if (cur == 3) cur = 0;
    }
    compute(cur);                      // tile KT-2
    waitbar<0>();                      // drain: tile KT-1 landed
    cur += 1; if (cur == 3) cur = 0;
    compute(cur);                      // tile KT-1

    int r0 = bm + wr * (TM / 2) + quad * 4;
    int c0 = bn + wc * (TN / 2) + l16;
    #pragma unroll
    for (int ni = 0; ni < NI; ++ni) {
        int gc = c0 + ni * 16;
        float bv = (MODE != 2) ? bias[gc] : 0.0f;
        #pragma unroll
        for (int mi = 0; mi < MI; ++mi) {
            int gr = r0 + mi * 16;
            if (MODE == 0 && gc >= 1536) {
                int hd = gc - 1536;
                int bb_ = gr >> 11, ss = gr & 2047;
                ushort4 o4;
                o4.x = f2b(acc[mi][ni][0] + bv);
                o4.y = f2b(acc[mi][ni][1] + bv);
                o4.z = f2b(acc[mi][ni][2] + bv);
                o4.w = f2b(acc[mi][ni][3] + bv);
                *(ushort4*)&vtb[((size_t)(bb_ * NH + (hd >> 6)) * 64 + (hd & 63)) * SEQ + ss] = o4;
            } else {
                #pragma unroll
                for (int reg = 0; reg < 4; ++reg) {
                    float v = acc[mi][ni][reg];
                    size_t idx = (size_t)(gr + reg) * N + gc;
                    if (MODE == 2) {
                        v = 0.5f * v * (1.0f + erff(v * 0.70710678118654752f));
                        ((unsigned short*)Cv)[idx] = f2b(v);
                    } else if (MODE == 0) {
                        v += bv;
                        if (gc < 768) v *= 0.125f;   // pre-scale Q (exact in bf16)
                        ((unsigned short*)Cv)[idx] = f2b(v);
                    } else {
                        ((float*)Cv)[idx] = v + bv + res[idx];
                    }
                }
            }
        }
    }
}

// ---------------------------------------------------------------- attention: MFMA flash
// ATQ=64 (768 blocks = 3/CU), XOR-swizzled K/V/Q LDS (pre-swizzled global src per rule 21)
#define ATQ 64
#define ATK 64
#define PTP 72
#define NQTA (SEQ/ATQ)  // 32
__global__ __launch_bounds__(256) void attn_mfma(const unsigned short* __restrict__ qkv,
                                                 const unsigned short* __restrict__ vt,
                                                 unsigned short* __restrict__ out) {
    __shared__ unsigned short Qs[ATQ * 64];          // 8KB  (swizzled)
    __shared__ unsigned short Ks[2][ATK * 64];       // 16KB (swizzled)
    __shared__ unsigned short Vts[2][64 * ATK];      // 16KB (swizzled)
    __shared__ unsigned short Pt[4][16 * PTP];       // 9KB  (linear, padded)

    int idx = blockIdx.x;
    int bh = idx % (BATCH * NH);
    int qt_blk = (NQTA - 1) - idx / (BATCH * NH);    // longest blocks first
    int b = bh / NH, hh = bh % NH;
    int qbase = qt_blk * ATQ;
    const size_t rstride = 3 * H;
    const unsigned short* base = qkv + (size_t)b * SEQ * rstride;
    const unsigned short* vbase = vt + (size_t)bh * DH * SEQ;

    int t = threadIdx.x;
    int w = t >> 6, lane = t & 63;
    int l16 = lane & 15, quad = lane >> 4;
    int lrow = lane >> 3;                            // 0..7 (row within 8-row gload group)
    int swsrc = ((lane & 7) ^ lrow) * 8;             // pre-swizzled source col (elements)
    int l7 = l16 & 7;                                // read-side XOR key

    auto stageKV = [&](int bb, int kt) {
        int k0 = kt * ATK;
        #pragma unroll
        for (int i = 0; i < 2; ++i) {
            int row = w * 16 + i * 8 + lrow;
            gload_lds16(base + (size_t)(k0 + row) * rstride + H + hh * 64 + swsrc,
                        (unsigned short*)Ks[bb] + w * 1024 + i * 512);
            gload_lds16(vbase + (size_t)row * SEQ + k0 + swsrc,
                        (unsigned short*)Vts[bb] + w * 1024 + i * 512);
        }
    };

    // stage Q (swizzled) and the first K/V tile, one drain
    #pragma unroll
    for (int i = 0; i < 2; ++i) {
        int row = w * 16 + i * 8 + lrow;
        gload_lds16(base + (size_t)(qbase + row) * rstride + hh * 64 + swsrc,
                    Qs + w * 1024 + i * 512);
    }
    stageKV(0, 0);
    __syncthreads();

    short8 qf[2];
    #pragma unroll
    for (int ch = 0; ch < 2; ++ch)
        qf[ch] = *(const short8*)&Qs[(w * 16 + l16) * 64 + ((ch * 4 + quad) ^ l7) * 8];

    float mst = -INFINITY;
    float lst = 0.0f;
    floatx4 oacc[4] = {};

    auto computeTile = [&](int bb, int kt) {
        int k0 = kt * ATK;
        floatx4 sacc[4] = {};
        __builtin_amdgcn_s_setprio(1);
        #pragma unroll
        for (int ch = 0; ch < 2; ++ch) {
            short8 kf[4];
            #pragma unroll
            for (int i = 0; i < 4; ++i)
                kf[i] = *(const short8*)&Ks[bb][(i * 16 + l16) * 64 + ((ch * 4 + quad) ^ l7) * 8];
            #pragma unroll
            for (int i = 0; i < 4; ++i)
                sacc[i] = __builtin_amdgcn_mfma_f32_16x16x32_bf16(kf[i], qf[ch], sacc[i], 0, 0, 0);
        }
        __builtin_amdgcn_s_setprio(0);

        bool needmask = (k0 + ATK - 1) > (qbase + w * 16);
        int qg = qbase + w * 16 + l16;
        float tm = -INFINITY;
        #pragma unroll
        for (int i = 0; i < 4; ++i)
            #pragma unroll
            for (int r = 0; r < 4; ++r) {
                float v = sacc[i][r];
                int kg = k0 + i * 16 + quad * 4 + r;
                if (needmask && kg > qg) v = -INFINITY;
                sacc[i][r] = v;
                tm = fmaxf(tm, v);
            }
        tm = fmaxf(tm, __shfl_xor(tm, 16));
        tm = fmaxf(tm, __shfl_xor(tm, 32));
        float mold = mst;
        float mnew = fmaxf(mold, tm);
        float alpha = __expf(mold - mnew);
        float suml = 0.0f;
        #pragma unroll
        for (int i = 0; i < 4; ++i) {
            float e0 = __expf(sacc[i][0] - mnew);
            float e1 = __expf(sacc[i][1] - mnew);
            float e2 = __expf(sacc[i][2] - mnew);
            float e3 = __expf(sacc[i][3] - mnew);
            suml += (e0 + e1) + (e2 + e3);
            uint2 u;
            u.x = (unsigned int)f2b(e0) | ((unsigned int)f2b(e1) << 16);
            u.y = (unsigned int)f2b(e2) | ((unsigned int)f2b(e3) << 16);
            *(uint2*)&Pt[w][l16 * PTP + i * 16 + quad * 4] = u;
        }
        suml += __shfl_xor(suml, 16);
        suml += __shfl_xor(suml, 32);
        lst = lst * alpha + suml;
        mst = mnew;
        #pragma unroll
        for (int r = 0; r < 4; ++r) {
            float ab = __shfl(alpha, quad * 4 + r);
            #pragma unroll
            for (int dt = 0; dt < 4; ++dt) oacc[dt][r] *= ab;
        }

        __builtin_amdgcn_s_setprio(1);
        #pragma unroll
        for (int ch = 0; ch < 2; ++ch) {
            short8 pf = *(const short8*)&Pt[w][l16 * PTP + ch * 32 + quad * 8];
            short8 vf[4];
            #pragma unroll
            for (int dt = 0; dt < 4; ++dt)
                vf[dt] = *(const short8*)&Vts[bb][(dt * 16 + l16) * 64 + ((ch * 4 + quad) ^ l7) * 8];
            #pragma unroll
            for (int dt = 0; dt < 4; ++dt)
                oacc[dt] = __builtin_amdgcn_mfma_f32_16x16x32_bf16(pf, vf[dt], oacc[dt], 0, 0, 0);
        }
        __builtin_amdgcn_s_setprio(0);
    };

    int ntiles = qt_blk + 1;   // may be odd
    for (int kt = 0; kt < ntiles; kt += 2) {
        if (kt + 1 < ntiles) stageKV(1, kt + 1);
        computeTile(0, kt);
        __syncthreads();
        if (kt + 1 < ntiles) {
            if (kt + 2 < ntiles) stageKV(0, kt + 2);
            computeTile(1, kt + 1);
            __syncthreads();
        }
    }

    #pragma unroll
    for (int r = 0; r < 4; ++r) {
        float lr = __shfl(lst, quad * 4 + r);
        float inv = 1.0f / lr;
        int qg = qbase + w * 16 + quad * 4 + r;
        #pragma unroll
        for (int dt = 0; dt < 4; ++dt)
            out[(size_t)(b * SEQ + qg) * H + hh * 64 + dt * 16 + l16] =
                f2b(oacc[dt][r] * inv);
    }
}

// ---------------------------------------------------------------- logits
__global__ __launch_bounds__(256) void logits_kernel(const float* __restrict__ xf,
                                                     const float* __restrict__ wte,
                                                     float* __restrict__ out) {
    int v = blockIdx.x * 4 + (threadIdx.x >> 6);
    if (v >= VOCAB) return;
    int lane = threadIdx.x & 63;
    const float* w = wte + (size_t)v * H + lane * 4;
    const float* x0 = xf + lane * 4;
    const float* x1 = xf + H + lane * 4;
    float4 w0 = *(const float4*)(w);
    float4 w1 = *(const float4*)(w + 256);
    float4 w2 = *(const float4*)(w + 512);
    float4 a0 = *(const float4*)(x0);
    float4 a1 = *(const float4*)(x0 + 256);
    float4 a2 = *(const float4*)(x0 + 512);
    float4 b0 = *(const float4*)(x1);
    float4 b1 = *(const float4*)(x1 + 256);
    float4 b2 = *(const float4*)(x1 + 512);
    float s0 = w0.x*a0.x + w0.y*a0.y + w0.z*a0.z + w0.w*a0.w
             + w1.x*a1.x + w1.y*a1.y + w1.z*a1.z + w1.w*a1.w
             + w2.x*a2.x + w2.y*a2.y + w2.z*a2.z + w2.w*a2.w;
    float s1 = w0.x*b0.x + w0.y*b0.y + w0.z*b0.z + w0.w*b0.w
             + w1.x*b1.x + w1.y*b1.y + w1.z*b1.z + w1.w*b1.w
             + w2.x*b2.x + w2.y*b2.y + w2.z*b2.z + w2.w*b2.w;
    #pragma unroll
    for (int off = 32; off > 0; off >>= 1) {
        s0 += __shfl_down(s0, off);
        s1 += __shfl_down(s1, off);
    }
    if (lane == 0) {
        out[v] = s0;
        out[VOCAB + v] = s1;
    }
}

// ---------------------------------------------------------------- launch
extern "C" void kernel_launch(void* const* d_in, const int* in_sizes, int n_in,
                              void* d_out, int out_size, void* d_ws, size_t ws_size,
                              hipStream_t stream) {
    const int*   ids     = (const int*)d_in[0];
    const float* wte     = (const float*)d_in[1];
    const float* wpe     = (const float*)d_in[2];
    const float* ln1_g   = (const float*)d_in[3];
    const float* ln1_b   = (const float*)d_in[4];
    const float* qkv_w   = (const float*)d_in[5];
    const float* qkv_b   = (const float*)d_in[6];
    const float* dense_w = (const float*)d_in[7];
    const float* dense_b = (const float*)d_in[8];
    const float* ln2_g   = (const float*)d_in[9];
    const float* ln2_b   = (const float*)d_in[10];
    const float* fc1_w   = (const float*)d_in[11];
    const float* fc2_w   = (const float*)d_in[12];
    const float* fc2_b   = (const float*)d_in[13];
    const float* lnf_g   = (const float*)d_in[14];
    const float* lnf_b   = (const float*)d_in[15];
    float* outp = (float*)d_out;

    char* p = (char*)d_ws;
    float* x             = (float*)p;          p += (size_t)TOK * H * 4;
    unsigned short* h    = (unsigned short*)p; p += (size_t)TOK * H * 2;
    unsigned short* qkvb = (unsigned short*)p; p += (size_t)TOK * 3 * H * 2;
    unsigned short* attnb= (unsigned short*)p; p += (size_t)TOK * H * 2;
    unsigned short* ab   = (unsigned short*)p; p += (size_t)TOK * 2 * H * 2;
    unsigned short* wt   = (unsigned short*)p; p += (size_t)WSTRIDE * LAYERS * 2;
    float* xf            = (float*)p;          p += (size_t)BATCH * H * 4;
    unsigned short* vtb  = ab;   // alias: ab unused between qkv-GEMM and fc1

    embed_kernel<<<TOK, 256, 0, stream>>>(ids, wte, wpe, x);
    wconv_all<<<LAYERS * 1152, 256, 0, stream>>>(qkv_w, dense_w, fc1_w, fc2_w, wt);

    for (int l = 0; l < LAYERS; ++l) {
        const unsigned short* wl = wt + (size_t)l * WSTRIDE;
        ln_kernel<true><<<TOK, 256, 0, stream>>>(x, ln1_g + l * H, ln1_b + l * H, h, 1, 0);
        gemm_bf16<64, 128, 0><<<dim3(2304 / 128, TOK / 64), 256, 0, stream>>>(
            h, wl + WOFF_QKV, qkv_b + l * 3 * H, nullptr, qkvb, vtb, TOK, 2304, 768);
        attn_mfma<<<BATCH * NH * NQTA, 256, 0, stream>>>(qkvb, vtb, attnb);
        gemm_bf16<64, 64, 1><<<dim3(768 / 64, TOK / 64), 256, 0, stream>>>(
            attnb, wl + WOFF_DENSE, dense_b + l * H, x, x, nullptr, TOK, 768, 768);
        ln_kernel<true><<<TOK, 256, 0, stream>>>(x, ln2_g + l * H, ln2_b + l * H, h, 1, 0);
        gemm_bf16<64, 128, 2><<<dim3(1536 / 128, TOK / 64), 256, 0, stream>>>(
            h, wl + WOFF_FC1, nullptr, nullptr, ab, nullptr, TOK, 1536, 768);
        gemm_bf16<64, 64, 1><<<dim3(768 / 64, TOK / 64), 256, 0, stream>>>(
            ab, wl + WOFF_FC2, fc2_b + l * H, x, x, nullptr, TOK, 768, 1536);
    }

    ln_kernel<false><<<BATCH, 256, 0, stream>>>(x, lnf_g, lnf_b, xf, SEQ, SEQ - 1);
    logits_kernel<<<(VOCAB + 3) / 4, 256, 0, stream>>>(xf, wte, outp);
}

// Round 7
// 1201.740 us; speedup vs baseline: 1.0470x; 1.0470x over previous
//
#include <hip/hip_runtime.h>
#include <math.h>

#define H 768
#define NH 12
#define DH 64
#define SEQ 2048
#define BATCH 2
#define TOK (BATCH*SEQ)   // 4096 rows
#define LAYERS 6
#define VOCAB 50257

// preconverted bf16 weight layout (per layer, element offsets)
#define WOFF_QKV   0
#define WSZ_QKV    (2304*768)
#define WOFF_DENSE (WOFF_QKV + WSZ_QKV)
#define WSZ_DENSE  (768*768)
#define WOFF_FC1   (WOFF_DENSE + WSZ_DENSE)
#define WSZ_FC1    (1536*768)
#define WOFF_FC2   (WOFF_FC1 + WSZ_FC1)
#define WSZ_FC2    (768*1536)
#define WSTRIDE    (WOFF_FC2 + WSZ_FC2)   // 4718592 elems/layer

typedef __attribute__((ext_vector_type(8))) short short8;
typedef __attribute__((ext_vector_type(4))) float floatx4;

__device__ __forceinline__ float bf2f(unsigned short u) {
    union { unsigned int i; float f; } v; v.i = ((unsigned int)u) << 16; return v.f;
}
__device__ __forceinline__ unsigned short f2b(float f) {
    union { float f; unsigned int i; } v; v.f = f;
    unsigned int u = v.i;
    return (unsigned short)((u + 0x7FFFu + ((u >> 16) & 1u)) >> 16);  // RNE
}
__device__ __forceinline__ void gload_lds16(const void* g, void* lds) {
    __builtin_amdgcn_global_load_lds((const __attribute__((address_space(1))) unsigned int*)g,
                                     (__attribute__((address_space(3))) unsigned int*)lds,
                                     16, 0, 0);
}

// ---------------------------------------------------------------- embed
__global__ __launch_bounds__(256) void embed_kernel(const int* __restrict__ ids,
                                                    const float* __restrict__ wte,
                                                    const float* __restrict__ wpe,
                                                    float* __restrict__ x) {
    int row = blockIdx.x;
    int s = row & (SEQ - 1);
    int id = ids[row];
    const float* wrow = wte + (size_t)id * H;
    const float* prow = wpe + (size_t)s * H;
    float* xrow = x + (size_t)row * H;
    for (int i = threadIdx.x; i < H; i += 256)
        xrow[i] = wrow[i] + prow[i];
}

// ---------------------------------------------------------------- layernorm
// one WAVE per row (12 elems/lane), 4 rows/block, zero barriers / zero LDS.
// out row index = r4 (compacted); input row = r4*rs + ro.
template <bool BF>
__global__ __launch_bounds__(256) void ln_kernel(const float* __restrict__ x,
                                                 const float* __restrict__ g,
                                                 const float* __restrict__ bb,
                                                 void* __restrict__ outv,
                                                 int nrows, int rs, int ro) {
    int r4 = blockIdx.x * 4 + (threadIdx.x >> 6);
    if (r4 >= nrows) return;
    int lane = threadIdx.x & 63;
    int row = r4 * rs + ro;
    const float* xr = x + (size_t)row * H + lane * 4;
    float4 a = *(const float4*)(xr);
    float4 b = *(const float4*)(xr + 256);
    float4 c = *(const float4*)(xr + 512);
    float s = (a.x + a.y + a.z + a.w) + (b.x + b.y + b.z + b.w) + (c.x + c.y + c.z + c.w);
    #pragma unroll
    for (int off = 32; off > 0; off >>= 1) s += __shfl_down(s, off);
    float m = __shfl(s, 0) * (1.0f / 768.0f);
    float da[12] = { a.x - m, a.y - m, a.z - m, a.w - m,
                     b.x - m, b.y - m, b.z - m, b.w - m,
                     c.x - m, c.y - m, c.z - m, c.w - m };
    float q = 0.0f;
    #pragma unroll
    for (int i = 0; i < 12; ++i) q += da[i] * da[i];
    #pragma unroll
    for (int off = 32; off > 0; off >>= 1) q += __shfl_down(q, off);
    float r = rsqrtf(__shfl(q, 0) * (1.0f / 768.0f) + 1e-12f);
    const float* gp = g + lane * 4;
    const float* bp = bb + lane * 4;
    float4 g0 = *(const float4*)(gp),       b0 = *(const float4*)(bp);
    float4 g1 = *(const float4*)(gp + 256), b1 = *(const float4*)(bp + 256);
    float4 g2 = *(const float4*)(gp + 512), b2 = *(const float4*)(bp + 512);
    float o[12] = { da[0]*r*g0.x + b0.x, da[1]*r*g0.y + b0.y, da[2]*r*g0.z + b0.z, da[3]*r*g0.w + b0.w,
                    da[4]*r*g1.x + b1.x, da[5]*r*g1.y + b1.y, da[6]*r*g1.z + b1.z, da[7]*r*g1.w + b1.w,
                    da[8]*r*g2.x + b2.x, da[9]*r*g2.y + b2.y, da[10]*r*g2.z + b2.z, da[11]*r*g2.w + b2.w };
    if (BF) {
        unsigned short* orow = (unsigned short*)outv + (size_t)r4 * H + lane * 4;
        #pragma unroll
        for (int ch = 0; ch < 3; ++ch) {
            ushort4 u;
            u.x = f2b(o[ch*4+0]); u.y = f2b(o[ch*4+1]);
            u.z = f2b(o[ch*4+2]); u.w = f2b(o[ch*4+3]);
            *(ushort4*)(orow + ch * 256) = u;
        }
    } else {
        float* orow = (float*)outv + (size_t)r4 * H + lane * 4;
        *(float4*)(orow)       = make_float4(o[0], o[1], o[2], o[3]);
        *(float4*)(orow + 256) = make_float4(o[4], o[5], o[6], o[7]);
        *(float4*)(orow + 512) = make_float4(o[8], o[9], o[10], o[11]);
    }
}

// ---------------------------------------------------------------- all-layer weight convert: fp32[K,N] -> bf16[N,K]
__global__ __launch_bounds__(256) void wconv_all(const float* __restrict__ qkv_w,
                                                 const float* __restrict__ dense_w,
                                                 const float* __restrict__ fc1_w,
                                                 const float* __restrict__ fc2_w,
                                                 unsigned short* __restrict__ wt) {
    __shared__ float tile[64][65];
    int bid = blockIdx.x;
    int l = bid / 1152;
    int r = bid % 1152;
    const float* W; unsigned short* D; int K, N, tn, tk;
    if (r < 432)      { W = qkv_w  + (size_t)l * 768 * 2304; D = wt + (size_t)l * WSTRIDE + WOFF_QKV;
                        K = 768;  N = 2304; tn = r % 36; tk = r / 36; }
    else if (r < 576) { r -= 432; W = dense_w + (size_t)l * 768 * 768; D = wt + (size_t)l * WSTRIDE + WOFF_DENSE;
                        K = 768;  N = 768;  tn = r % 12; tk = r / 12; }
    else if (r < 864) { r -= 576; W = fc1_w + (size_t)l * 768 * 1536; D = wt + (size_t)l * WSTRIDE + WOFF_FC1;
                        K = 768;  N = 1536; tn = r % 24; tk = r / 24; }
    else              { r -= 864; W = fc2_w + (size_t)l * 1536 * 768; D = wt + (size_t)l * WSTRIDE + WOFF_FC2;
                        K = 1536; N = 768;  tn = r % 12; tk = r / 12; }
    int n0 = tn * 64, k0 = tk * 64;
    int t = threadIdx.x;
    int rr = t >> 4, c = (t & 15) << 2;
    #pragma unroll
    for (int i = 0; i < 4; ++i) {
        float4 v = *(const float4*)(W + (size_t)(k0 + rr + 16 * i) * N + n0 + c);
        tile[rr + 16 * i][c + 0] = v.x; tile[rr + 16 * i][c + 1] = v.y;
        tile[rr + 16 * i][c + 2] = v.z; tile[rr + 16 * i][c + 3] = v.w;
    }
    __syncthreads();
    #pragma unroll
    for (int i = 0; i < 4; ++i) {
        int n = rr + 16 * i;
        ushort4 o;
        o.x = f2b(tile[c + 0][n]); o.y = f2b(tile[c + 1][n]);
        o.z = f2b(tile[c + 2][n]); o.w = f2b(tile[c + 3][n]);
        *(ushort4*)(D + (size_t)(n0 + n) * K + k0 + c) = o;
    }
}

// ---------------------------------------------------------------- bf16 MFMA GEMM, GBK=64, XOR-swizzled LDS, 2-phase dbuf
// (round-4 verified structure; counted-vmcnt 3-buf pipeline REGRESSED — reverted)
// C[M,N] = A[M,K] @ Bt[N,K]^T
// MODE 0: qkv epilogue (+bias; Q cols pre-scaled 1/8; V cols -> vtb transposed) -> bf16
// MODE 1: +bias+res -> fp32 ; MODE 2: gelu -> bf16
#define GBK 64
template <int TM, int TN, int MODE>
__global__ __launch_bounds__(256) void gemm_bf16(const unsigned short* __restrict__ A,
                                                 const unsigned short* __restrict__ Bt,
                                                 const float* __restrict__ bias,
                                                 const float* __restrict__ res,
                                                 void* __restrict__ Cv,
                                                 unsigned short* __restrict__ vtb,
                                                 int M, int N, int K) {
    constexpr int MI = TM / 32, NI = TN / 32;
    constexpr int ALD = TM / 32, BLD = TN / 32;   // 8-row gloads per wave
    __shared__ short As[2][TM * GBK];
    __shared__ short Bs[2][TN * GBK];
    int t = threadIdx.x;
    int w = t >> 6, lane = t & 63;
    int wr = w >> 1, wc = w & 1;
    int l16 = lane & 15, quad = lane >> 4;
    int l7 = l16 & 7;
    int lrow = lane >> 3;                         // 0..7
    int swsrc = ((lane & 7) ^ lrow) * 8;          // pre-swizzled source col
    int bm = blockIdx.y * TM, bn = blockIdx.x * TN;

    floatx4 acc[MI][NI] = {};
    const unsigned short* Aw[ALD];
    const unsigned short* Bw[BLD];
    #pragma unroll
    for (int j = 0; j < ALD; ++j)
        Aw[j] = A + (size_t)(bm + w * (TM / 4) + j * 8 + lrow) * K + swsrc;
    #pragma unroll
    for (int j = 0; j < BLD; ++j)
        Bw[j] = Bt + (size_t)(bn + w * (TN / 4) + j * 8 + lrow) * K + swsrc;

    auto stage = [&](int b, int k0) {
        #pragma unroll
        for (int j = 0; j < ALD; ++j)
            gload_lds16(Aw[j] + k0, (char*)&As[b][0] + (w * (TM / 4) + j * 8) * (GBK * 2));
        #pragma unroll
        for (int j = 0; j < BLD; ++j)
            gload_lds16(Bw[j] + k0, (char*)&Bs[b][0] + (w * (TN / 4) + j * 8) * (GBK * 2));
    };
    auto compute = [&](int b) {
        short8 af[2][MI], bfr[2][NI];
        #pragma unroll
        for (int kk = 0; kk < 2; ++kk) {
            #pragma unroll
            for (int mi = 0; mi < MI; ++mi)
                af[kk][mi] = *(const short8*)&As[b][(wr * (TM / 2) + mi * 16 + l16) * GBK + ((kk * 4 + quad) ^ l7) * 8];
            #pragma unroll
            for (int ni = 0; ni < NI; ++ni)
                bfr[kk][ni] = *(const short8*)&Bs[b][(wc * (TN / 2) + ni * 16 + l16) * GBK + ((kk * 4 + quad) ^ l7) * 8];
        }
        #pragma unroll
        for (int kk = 0; kk < 2; ++kk)
            #pragma unroll
            for (int mi = 0; mi < MI; ++mi)
                #pragma unroll
                for (int ni = 0; ni < NI; ++ni)
                    acc[mi][ni] = __builtin_amdgcn_mfma_f32_16x16x32_bf16(af[kk][mi], bfr[kk][ni], acc[mi][ni], 0, 0, 0);
    };

    stage(0, 0);
    __syncthreads();
    const int KT = K / GBK;   // 12 or 24: always even
    for (int kt = 0; kt < KT; kt += 2) {
        stage(1, (kt + 1) * GBK);
        compute(0);
        __syncthreads();
        if (kt + 2 < KT) stage(0, (kt + 2) * GBK);
        compute(1);
        __syncthreads();
    }

    int r0 = bm + wr * (TM / 2) + quad * 4;
    int c0 = bn + wc * (TN / 2) + l16;
    #pragma unroll
    for (int ni = 0; ni < NI; ++ni) {
        int gc = c0 + ni * 16;
        float bv = (MODE != 2) ? bias[gc] : 0.0f;
        #pragma unroll
        for (int mi = 0; mi < MI; ++mi) {
            int gr = r0 + mi * 16;
            if (MODE == 0 && gc >= 1536) {
                int hd = gc - 1536;
                int bb_ = gr >> 11, ss = gr & 2047;
                ushort4 o4;
                o4.x = f2b(acc[mi][ni][0] + bv);
                o4.y = f2b(acc[mi][ni][1] + bv);
                o4.z = f2b(acc[mi][ni][2] + bv);
                o4.w = f2b(acc[mi][ni][3] + bv);
                *(ushort4*)&vtb[((size_t)(bb_ * NH + (hd >> 6)) * 64 + (hd & 63)) * SEQ + ss] = o4;
            } else {
                #pragma unroll
                for (int reg = 0; reg < 4; ++reg) {
                    float v = acc[mi][ni][reg];
                    size_t idx = (size_t)(gr + reg) * N + gc;
                    if (MODE == 2) {
                        v = 0.5f * v * (1.0f + erff(v * 0.70710678118654752f));
                        ((unsigned short*)Cv)[idx] = f2b(v);
                    } else if (MODE == 0) {
                        v += bv;
                        if (gc < 768) v *= 0.125f;   // pre-scale Q (exact in bf16)
                        ((unsigned short*)Cv)[idx] = f2b(v);
                    } else {
                        ((float*)Cv)[idx] = v + bv + res[idx];
                    }
                }
            }
        }
    }
}

// ---------------------------------------------------------------- attention: MFMA flash
// ATQ=64 (768 blocks = 3/CU), XOR-swizzled K/V/Q LDS (pre-swizzled global src per rule 21)
#define ATQ 64
#define ATK 64
#define PTP 72
#define NQTA (SEQ/ATQ)  // 32
__global__ __launch_bounds__(256) void attn_mfma(const unsigned short* __restrict__ qkv,
                                                 const unsigned short* __restrict__ vt,
                                                 unsigned short* __restrict__ out) {
    __shared__ unsigned short Qs[ATQ * 64];          // 8KB  (swizzled)
    __shared__ unsigned short Ks[2][ATK * 64];       // 16KB (swizzled)
    __shared__ unsigned short Vts[2][64 * ATK];      // 16KB (swizzled)
    __shared__ unsigned short Pt[4][16 * PTP];       // 9KB  (linear, padded)

    int idx = blockIdx.x;
    int bh = idx % (BATCH * NH);
    int qt_blk = (NQTA - 1) - idx / (BATCH * NH);    // longest blocks first
    int b = bh / NH, hh = bh % NH;
    int qbase = qt_blk * ATQ;
    const size_t rstride = 3 * H;
    const unsigned short* base = qkv + (size_t)b * SEQ * rstride;
    const unsigned short* vbase = vt + (size_t)bh * DH * SEQ;

    int t = threadIdx.x;
    int w = t >> 6, lane = t & 63;
    int l16 = lane & 15, quad = lane >> 4;
    int lrow = lane >> 3;                            // 0..7 (row within 8-row gload group)
    int swsrc = ((lane & 7) ^ lrow) * 8;             // pre-swizzled source col (elements)
    int l7 = l16 & 7;                                // read-side XOR key

    auto stageKV = [&](int bb, int kt) {
        int k0 = kt * ATK;
        #pragma unroll
        for (int i = 0; i < 2; ++i) {
            int row = w * 16 + i * 8 + lrow;
            gload_lds16(base + (size_t)(k0 + row) * rstride + H + hh * 64 + swsrc,
                        (unsigned short*)Ks[bb] + w * 1024 + i * 512);
            gload_lds16(vbase + (size_t)row * SEQ + k0 + swsrc,
                        (unsigned short*)Vts[bb] + w * 1024 + i * 512);
        }
    };

    // stage Q (swizzled) and the first K/V tile, one drain
    #pragma unroll
    for (int i = 0; i < 2; ++i) {
        int row = w * 16 + i * 8 + lrow;
        gload_lds16(base + (size_t)(qbase + row) * rstride + hh * 64 + swsrc,
                    Qs + w * 1024 + i * 512);
    }
    stageKV(0, 0);
    __syncthreads();

    short8 qf[2];
    #pragma unroll
    for (int ch = 0; ch < 2; ++ch)
        qf[ch] = *(const short8*)&Qs[(w * 16 + l16) * 64 + ((ch * 4 + quad) ^ l7) * 8];

    float mst = -INFINITY;
    float lst = 0.0f;
    floatx4 oacc[4] = {};

    auto computeTile = [&](int bb, int kt) {
        int k0 = kt * ATK;
        floatx4 sacc[4] = {};
        __builtin_amdgcn_s_setprio(1);
        #pragma unroll
        for (int ch = 0; ch < 2; ++ch) {
            short8 kf[4];
            #pragma unroll
            for (int i = 0; i < 4; ++i)
                kf[i] = *(const short8*)&Ks[bb][(i * 16 + l16) * 64 + ((ch * 4 + quad) ^ l7) * 8];
            #pragma unroll
            for (int i = 0; i < 4; ++i)
                sacc[i] = __builtin_amdgcn_mfma_f32_16x16x32_bf16(kf[i], qf[ch], sacc[i], 0, 0, 0);
        }
        __builtin_amdgcn_s_setprio(0);

        bool needmask = (k0 + ATK - 1) > (qbase + w * 16);
        int qg = qbase + w * 16 + l16;
        float tm = -INFINITY;
        #pragma unroll
        for (int i = 0; i < 4; ++i)
            #pragma unroll
            for (int r = 0; r < 4; ++r) {
                float v = sacc[i][r];
                int kg = k0 + i * 16 + quad * 4 + r;
                if (needmask && kg > qg) v = -INFINITY;
                sacc[i][r] = v;
                tm = fmaxf(tm, v);
            }
        tm = fmaxf(tm, __shfl_xor(tm, 16));
        tm = fmaxf(tm, __shfl_xor(tm, 32));
        float mold = mst;
        float mnew = fmaxf(mold, tm);
        float alpha = __expf(mold - mnew);
        float suml = 0.0f;
        #pragma unroll
        for (int i = 0; i < 4; ++i) {
            float e0 = __expf(sacc[i][0] - mnew);
            float e1 = __expf(sacc[i][1] - mnew);
            float e2 = __expf(sacc[i][2] - mnew);
            float e3 = __expf(sacc[i][3] - mnew);
            suml += (e0 + e1) + (e2 + e3);
            uint2 u;
            u.x = (unsigned int)f2b(e0) | ((unsigned int)f2b(e1) << 16);
            u.y = (unsigned int)f2b(e2) | ((unsigned int)f2b(e3) << 16);
            *(uint2*)&Pt[w][l16 * PTP + i * 16 + quad * 4] = u;
        }
        suml += __shfl_xor(suml, 16);
        suml += __shfl_xor(suml, 32);
        lst = lst * alpha + suml;
        mst = mnew;
        #pragma unroll
        for (int r = 0; r < 4; ++r) {
            float ab = __shfl(alpha, quad * 4 + r);
            #pragma unroll
            for (int dt = 0; dt < 4; ++dt) oacc[dt][r] *= ab;
        }

        __builtin_amdgcn_s_setprio(1);
        #pragma unroll
        for (int ch = 0; ch < 2; ++ch) {
            short8 pf = *(const short8*)&Pt[w][l16 * PTP + ch * 32 + quad * 8];
            short8 vf[4];
            #pragma unroll
            for (int dt = 0; dt < 4; ++dt)
                vf[dt] = *(const short8*)&Vts[bb][(dt * 16 + l16) * 64 + ((ch * 4 + quad) ^ l7) * 8];
            #pragma unroll
            for (int dt = 0; dt < 4; ++dt)
                oacc[dt] = __builtin_amdgcn_mfma_f32_16x16x32_bf16(pf, vf[dt], oacc[dt], 0, 0, 0);
        }
        __builtin_amdgcn_s_setprio(0);
    };

    int ntiles = qt_blk + 1;   // may be odd
    for (int kt = 0; kt < ntiles; kt += 2) {
        if (kt + 1 < ntiles) stageKV(1, kt + 1);
        computeTile(0, kt);
        __syncthreads();
        if (kt + 1 < ntiles) {
            if (kt + 2 < ntiles) stageKV(0, kt + 2);
            computeTile(1, kt + 1);
            __syncthreads();
        }
    }

    #pragma unroll
    for (int r = 0; r < 4; ++r) {
        float lr = __shfl(lst, quad * 4 + r);
        float inv = 1.0f / lr;
        int qg = qbase + w * 16 + quad * 4 + r;
        #pragma unroll
        for (int dt = 0; dt < 4; ++dt)
            out[(size_t)(b * SEQ + qg) * H + hh * 64 + dt * 16 + l16] =
                f2b(oacc[dt][r] * inv);
    }
}

// ---------------------------------------------------------------- logits
__global__ __launch_bounds__(256) void logits_kernel(const float* __restrict__ xf,
                                                     const float* __restrict__ wte,
                                                     float* __restrict__ out) {
    int v = blockIdx.x * 4 + (threadIdx.x >> 6);
    if (v >= VOCAB) return;
    int lane = threadIdx.x & 63;
    const float* w = wte + (size_t)v * H + lane * 4;
    const float* x0 = xf + lane * 4;
    const float* x1 = xf + H + lane * 4;
    float4 w0 = *(const float4*)(w);
    float4 w1 = *(const float4*)(w + 256);
    float4 w2 = *(const float4*)(w + 512);
    float4 a0 = *(const float4*)(x0);
    float4 a1 = *(const float4*)(x0 + 256);
    float4 a2 = *(const float4*)(x0 + 512);
    float4 b0 = *(const float4*)(x1);
    float4 b1 = *(const float4*)(x1 + 256);
    float4 b2 = *(const float4*)(x1 + 512);
    float s0 = w0.x*a0.x + w0.y*a0.y + w0.z*a0.z + w0.w*a0.w
             + w1.x*a1.x + w1.y*a1.y + w1.z*a1.z + w1.w*a1.w
             + w2.x*a2.x + w2.y*a2.y + w2.z*a2.z + w2.w*a2.w;
    float s1 = w0.x*b0.x + w0.y*b0.y + w0.z*b0.z + w0.w*b0.w
             + w1.x*b1.x + w1.y*b1.y + w1.z*b1.z + w1.w*b1.w
             + w2.x*b2.x + w2.y*b2.y + w2.z*b2.z + w2.w*b2.w;
    #pragma unroll
    for (int off = 32; off > 0; off >>= 1) {
        s0 += __shfl_down(s0, off);
        s1 += __shfl_down(s1, off);
    }
    if (lane == 0) {
        out[v] = s0;
        out[VOCAB + v] = s1;
    }
}

// ---------------------------------------------------------------- launch
extern "C" void kernel_launch(void* const* d_in, const int* in_sizes, int n_in,
                              void* d_out, int out_size, void* d_ws, size_t ws_size,
                              hipStream_t stream) {
    const int*   ids     = (const int*)d_in[0];
    const float* wte     = (const float*)d_in[1];
    const float* wpe     = (const float*)d_in[2];
    const float* ln1_g   = (const float*)d_in[3];
    const float* ln1_b   = (const float*)d_in[4];
    const float* qkv_w   = (const float*)d_in[5];
    const float* qkv_b   = (const float*)d_in[6];
    const float* dense_w = (const float*)d_in[7];
    const float* dense_b = (const float*)d_in[8];
    const float* ln2_g   = (const float*)d_in[9];
    const float* ln2_b   = (const float*)d_in[10];
    const float* fc1_w   = (const float*)d_in[11];
    const float* fc2_w   = (const float*)d_in[12];
    const float* fc2_b   = (const float*)d_in[13];
    const float* lnf_g   = (const float*)d_in[14];
    const float* lnf_b   = (const float*)d_in[15];
    float* outp = (float*)d_out;

    char* p = (char*)d_ws;
    float* x             = (float*)p;          p += (size_t)TOK * H * 4;
    unsigned short* h    = (unsigned short*)p; p += (size_t)TOK * H * 2;
    unsigned short* qkvb = (unsigned short*)p; p += (size_t)TOK * 3 * H * 2;
    unsigned short* attnb= (unsigned short*)p; p += (size_t)TOK * H * 2;
    unsigned short* ab   = (unsigned short*)p; p += (size_t)TOK * 2 * H * 2;
    unsigned short* wt   = (unsigned short*)p; p += (size_t)WSTRIDE * LAYERS * 2;
    float* xf            = (float*)p;          p += (size_t)BATCH * H * 4;
    unsigned short* vtb  = ab;   // alias: ab unused between qkv-GEMM and fc1

    embed_kernel<<<TOK, 256, 0, stream>>>(ids, wte, wpe, x);
    wconv_all<<<LAYERS * 1152, 256, 0, stream>>>(qkv_w, dense_w, fc1_w, fc2_w, wt);

    for (int l = 0; l < LAYERS; ++l) {
        const unsigned short* wl = wt + (size_t)l * WSTRIDE;
        ln_kernel<true><<<TOK / 4, 256, 0, stream>>>(x, ln1_g + l * H, ln1_b + l * H, h, TOK, 1, 0);
        gemm_bf16<64, 128, 0><<<dim3(2304 / 128, TOK / 64), 256, 0, stream>>>(
            h, wl + WOFF_QKV, qkv_b + l * 3 * H, nullptr, qkvb, vtb, TOK, 2304, 768);
        attn_mfma<<<BATCH * NH * NQTA, 256, 0, stream>>>(qkvb, vtb, attnb);
        gemm_bf16<64, 64, 1><<<dim3(768 / 64, TOK / 64), 256, 0, stream>>>(
            attnb, wl + WOFF_DENSE, dense_b + l * H, x, x, nullptr, TOK, 768, 768);
        ln_kernel<true><<<TOK / 4, 256, 0, stream>>>(x, ln2_g + l * H, ln2_b + l * H, h, TOK, 1, 0);
        gemm_bf16<64, 128, 2><<<dim3(1536 / 128, TOK / 64), 256, 0, stream>>>(
            h, wl + WOFF_FC1, nullptr, nullptr, ab, nullptr, TOK, 1536, 768);
        gemm_bf16<64, 64, 1><<<dim3(768 / 64, TOK / 64), 256, 0, stream>>>(
            ab, wl + WOFF_FC2, fc2_b + l * H, x, x, nullptr, TOK, 768, 1536);
    }

    ln_kernel<false><<<1, 256, 0, stream>>>(x, lnf_g, lnf_b, xf, BATCH, SEQ, SEQ - 1);
    logits_kernel<<<(VOCAB + 3) / 4, 256, 0, stream>>>(xf, wte, outp);
}